// Round 10
// baseline (672.696 us; speedup 1.0000x reference)
//
#include <hip/hip_runtime.h>
#include <cmath>

#define B_ 1024
#define CIN_ 22
#define T1_ 438
#define COUT_ 20
#define T2_ 439

// ws float offsets
#define OFF_S 0
#define OFF_M 32
#define OFF_SUM2 576
#define OFF_SSQ2 608
#define OFF_A2 640
#define OFF_ACC_END 704
#define OFF_C 1024
#define OFF_LQ (OFF_C + B_*3*400)
#define OFF_LK (OFF_LQ + B_*3*324)
#define OFF_LV (OFF_LK + B_*3*324)
#define OFF_WEFF (OFF_LV + B_*3*324)
#define OFF_BPRE (OFF_WEFF + 5280)

__global__ __launch_bounds__(256) void k_zero(float* ws){
  for(int i=threadIdx.x; i<OFF_ACC_END; i+=256) ws[i]=0.f;
}

// bn1 stats via second-moment matrix of x: S[22], M[22][22] (triu), float4 dots
__global__ __launch_bounds__(256) void k_moment(const float* __restrict__ x, float* __restrict__ ws){
  __shared__ float xs[CIN_][440];
  int b=blockIdx.x;
  const float* xb = x + (size_t)b*CIN_*T1_;
  for(int i=threadIdx.x;i<CIN_*T1_;i+=256){
    int h=i/T1_, t=i-h*T1_;
    xs[h][t]=xb[i];
  }
  if(threadIdx.x<CIN_){ xs[threadIdx.x][438]=0.f; xs[threadIdx.x][439]=0.f; }
  __syncthreads();
  for(int tgt=threadIdx.x; tgt<275; tgt+=256){
    if(tgt<253){
      int r=tgt, i=0;
      while(true){ int c=CIN_-i; if(r<c) break; r-=c; i++; }
      int j=i+r;
      const float4* ri=(const float4*)&xs[i][0];
      const float4* rj=(const float4*)&xs[j][0];
      float acc=0.f;
      for(int t=0;t<110;t++){
        float4 a=ri[t], bb=rj[t];
        acc += a.x*bb.x + a.y*bb.y + a.z*bb.z + a.w*bb.w;
      }
      atomicAdd(&ws[OFF_M + i*CIN_ + j], acc);
    } else {
      int c=tgt-253;
      const float4* rc=(const float4*)&xs[c][0];
      float acc=0.f;
      for(int t=0;t<110;t++){
        float4 a=rc[t];
        acc += a.x + a.y + a.z + a.w;
      }
      atomicAdd(&ws[OFF_S + c], acc);
    }
  }
}

// bn1 closed-form + fold conv1/bn1 into conv2: Weff[o][h][k], bias prefix pre[o][13]
__global__ __launch_bounds__(256) void k_prep(const float* __restrict__ w1, const float* __restrict__ cb1,
                                              const float* __restrict__ g1, const float* __restrict__ bb1,
                                              const float* __restrict__ w2, float* __restrict__ ws){
  __shared__ float a1s[CIN_], e1s[CIN_];
  int tid=threadIdx.x;
  if(tid<CIN_){
    int c=tid;
    const double N = (double)B_*T1_;
    double wS=0.0, wMw=0.0;
    for(int h=0;h<CIN_;h++) wS += (double)w1[c*CIN_+h]*(double)ws[OFF_S+h];
    for(int h=0;h<CIN_;h++){
      for(int h2=0;h2<CIN_;h2++){
        int i=h<h2?h:h2, j=h<h2?h2:h;
        wMw += (double)w1[c*CIN_+h]*(double)w1[c*CIN_+h2]*(double)ws[OFF_M+i*CIN_+j];
      }
    }
    double bc=cb1[c];
    double mean=wS/N+bc;
    double ex2=(wMw+2.0*bc*wS)/N+bc*bc;
    double var=ex2-mean*mean;
    double a1=(double)g1[c]/sqrt(var+1e-5);
    double d1=(double)bb1[c]-mean*a1;
    a1s[c]=(float)a1;
    e1s[c]=(float)(a1*bc+d1);
  }
  __syncthreads();
  for(int idx=tid; idx<5280; idx+=256){
    int o=idx/264, r=idx-o*264, h=r/12, k=r-h*12;
    float s=0.f;
    for(int i=0;i<CIN_;i++) s += w2[(o*CIN_+i)*12+k]*a1s[i]*w1[i*CIN_+h];
    ws[OFF_WEFF+idx]=s;
  }
  if(tid<COUT_){
    float pre=0.f;
    ws[OFF_BPRE+tid*13+0]=0.f;
    for(int k=0;k<12;k++){
      float wb=0.f;
      for(int i=0;i<CIN_;i++) wb += w2[(tid*CIN_+i)*12+k]*e1s[i];
      pre += wb;
      ws[OFF_BPRE+tid*13+k+1]=pre;
    }
  }
}

// direct conv x->h2 (folded kernel) + per-patch covariance + bn2 sums.
__global__ __launch_bounds__(256) void k_cov(const float* __restrict__ x,
                                             float* __restrict__ ws){
  __shared__ float Wl[5280];
  __shared__ float preL[COUT_][13];
  __shared__ float xs[CIN_][168];
  __shared__ float h2w[COUT_][156];
  __shared__ float pmu[COUT_];
  int b=blockIdx.x, tid=threadIdx.x;
  for(int i=tid;i<5280;i+=256) Wl[i]=ws[OFF_WEFF+i];
  for(int i=tid;i<260;i+=256) ((float*)preL)[i]=ws[OFF_BPRE+i];
  int pi=0,pj=0;
  if(tid<210){ int r=tid,i=0; while(true){int c=COUT_-i; if(r<c)break; r-=c; i++;} pi=i; pj=i+r; }
  int sc = tid-210;
  float ac1=0.f, ac2=0.f;
  const float* xb = x + (size_t)b*CIN_*T1_;
  int o = tid/12, cch = tid-12*o;
  int t0 = cch*13;
  for(int p=0;p<3;p++){
    const int off = (p==0)?0:((p==1)?147:293);
    const int L = (p==0)?147:146;
    __syncthreads();
    for(int idx=tid; idx<CIN_*168; idx+=256){
      int h=idx/168, c2=idx-h*168;
      int gxt = off-6+c2;
      xs[h][c2] = (c2<167 && gxt>=0 && gxt<T1_) ? xb[h*T1_+gxt] : 0.f;
    }
    __syncthreads();
    if(tid<240){
      float acc[13];
      #pragma unroll
      for(int j=0;j<13;j++){
        int gt = off+t0+j;
        int kmin = 6-gt; kmin = kmin<0?0:kmin;
        int kmax = 443-gt; kmax = kmax>11?11:kmax;
        acc[j] = (kmax>=kmin)? preL[o][kmax+1]-preL[o][kmin] : 0.f;
      }
      const float* Wo = &Wl[o*264];
      for(int h=0;h<CIN_;h++){
        float xw[24];
        #pragma unroll
        for(int c2=0;c2<24;c2++) xw[c2]=xs[h][t0+c2];
        const float* Wh = Wo + h*12;
        #pragma unroll
        for(int k=0;k<12;k++){
          float w=Wh[k];
          #pragma unroll
          for(int j=0;j<13;j++) acc[j] += w*xw[j+k];
        }
      }
      #pragma unroll
      for(int j=0;j<13;j++) if(t0+j<L) h2w[o][t0+j]=acc[j];
    } else {
      int npad = 156-L;
      for(int z=tid-240; z<COUT_*npad; z+=16){
        int oo=z/npad, c2=z-oo*npad;
        h2w[oo][L+c2]=0.f;
      }
    }
    __syncthreads();
    float s=0.f;
    if(tid<210){
      const float4* ri=(const float4*)&h2w[pi][0];
      const float4* rj=(const float4*)&h2w[pj][0];
      for(int t=0;t<39;t++){
        float4 a=ri[t], bb=rj[t];
        s += a.x*bb.x + a.y*bb.y + a.z*bb.z + a.w*bb.w;
      }
    } else if(sc>=0 && sc<COUT_){
      const float4* rc=(const float4*)&h2w[sc][0];
      float s1=0.f,s2=0.f;
      for(int t=0;t<39;t++){
        float4 a=rc[t];
        s1 += a.x+a.y+a.z+a.w;
        s2 += a.x*a.x+a.y*a.y+a.z*a.z+a.w*a.w;
      }
      ac1+=s1; ac2+=s2; pmu[sc]=s1/(float)L;
    }
    __syncthreads();
    if(tid<210){
      s -= (float)L*pmu[pi]*pmu[pj];
      float* Cb = ws + OFF_C + ((size_t)b*3+p)*400;
      Cb[pi*COUT_+pj]=s; Cb[pj*COUT_+pi]=s;
    }
  }
  if(sc>=0 && sc<COUT_){
    atomicAdd(&ws[OFF_SUM2+sc], ac1);
    atomicAdd(&ws[OFF_SSQ2+sc], ac2);
  }
}

__global__ void k_fin2(const float* __restrict__ g2, float* __restrict__ ws){
  int c=threadIdx.x; if(c>=COUT_) return;
  const double N=(double)B_*T2_;
  double m=ws[OFF_SUM2+c]/N;
  double v=ws[OFF_SSQ2+c]/N - m*m;
  ws[OFF_A2+c]=(float)((double)g2[c]/sqrt(v+1e-5));
}

// ---------------------------------------------------------------------------
// Brent-Luk one-sided Jacobi, columns-in-lanes, TWO matrices interleaved per
// 9-lane group (ILP-2: matrix B's VALU work fills matrix A's bpermute-latency
// shadow). Batched shuffle phases; __launch_bounds__(64,1) on callers lifts
// the VGPR cap (R9 found VGPR=88 forced shuffle serialization ~50cyc each).
// ---------------------------------------------------------------------------
__device__ __forceinline__ void bl_jacobi2(float PA[18], float QA[18],
                                           float PB[18], float QB[18],
                                           float &dgpa, float &dgqa,
                                           float &dgpb, float &dgqb,
                                           int l9, int srcP, int srcQ, int maxsweep){
  for(int sweep=0; sweep<maxsweep; sweep++){
    { float n0=0.f,n1=0.f,m0=0.f,m1=0.f,o0=0.f,o1=0.f,p0=0.f,p1=0.f;
      #pragma unroll
      for(int k=0;k<18;k+=2){
        n0+=PA[k]*PA[k]; n1+=PA[k+1]*PA[k+1];
        m0+=QA[k]*QA[k]; m1+=QA[k+1]*QA[k+1];
        o0+=PB[k]*PB[k]; o1+=PB[k+1]*PB[k+1];
        p0+=QB[k]*QB[k]; p1+=QB[k+1]*QB[k+1];
      }
      dgpa=n0+n1; dgqa=m0+m1; dgpb=o0+o1; dgqb=p0+p1;
    }
    float smax = 0.f;
    for(int r=0;r<17;r++){
      float a0=0.f,a1=0.f,b0=0.f,b1=0.f;
      #pragma unroll
      for(int k=0;k<18;k+=2){
        a0 += PA[k]*QA[k]; a1 += PA[k+1]*QA[k+1];
        b0 += PB[k]*QB[k]; b1 += PB[k+1]*QB[k+1];
      }
      float apqA = a0+a1, apqB = b0+b1;
      float tauA = __fdividef(dgqa-dgpa, 2.f*apqA);
      float tauB = __fdividef(dgqb-dgpb, 2.f*apqB);
      float ttA  = __fdividef(copysignf(1.f,tauA), fabsf(tauA)+sqrtf(1.f+tauA*tauA));
      float ttB  = __fdividef(copysignf(1.f,tauB), fabsf(tauB)+sqrtf(1.f+tauB*tauB));
      float cA   = rsqrtf(1.f+ttA*ttA), cB = rsqrtf(1.f+ttB*ttB);
      float sA   = ttA*cA,              sB = ttB*cB;
      bool  zA   = (apqA==0.f),         zB = (apqB==0.f);
      ttA = zA?0.f:ttA; cA = zA?1.f:cA; sA = zA?0.f:sA;
      ttB = zB?0.f:ttB; cB = zB?1.f:cB; sB = zB?0.f:sB;
      float ndgpa = dgpa - ttA*apqA, ndgqa = dgqa + ttA*apqA;
      float ndgpb = dgpb - ttB*apqB, ndgqb = dgqb + ttB*apqB;
      smax = fmaxf(smax, fmaxf(fabsf(sA), fabsf(sB)));
      float rpA[18], rqA[18], rpB[18], rqB[18];
      #pragma unroll
      for(int k=0;k<18;k++){
        float xa=PA[k], ya=QA[k], xb=PB[k], yb=QB[k];
        rpA[k]=cA*xa-sA*ya; rqA[k]=sA*xa+cA*ya;
        rpB[k]=cB*xb-sB*yb; rqB[k]=sB*xb+cB*yb;
      }
      float npA[18], npB[18], nqA[18], nqB[18];
      #pragma unroll
      for(int k=0;k<18;k++){
        npA[k]=__shfl(rpA[k], srcP);
        npB[k]=__shfl(rpB[k], srcP);
      }
      #pragma unroll
      for(int k=0;k<18;k++){
        float sqa=(l9==0)?rpA[k]:rqA[k];
        float sqb=(l9==0)?rpB[k]:rqB[k];
        nqA[k]=__shfl(sqa, srcQ);
        nqB[k]=__shfl(sqb, srcQ);
      }
      #pragma unroll
      for(int k=0;k<18;k++){
        PA[k]=(l9==8)?rqA[k]:npA[k];  QA[k]=(l9==0)?rqA[k]:nqA[k];
        PB[k]=(l9==8)?rqB[k]:npB[k];  QB[k]=(l9==0)?rqB[k]:nqB[k];
      }
      {
        float npa=__shfl(ndgpa,srcP), npb=__shfl(ndgpb,srcP);
        float sqa=(l9==0)?ndgpa:ndgqa, sqb=(l9==0)?ndgpb:ndgqb;
        float nqa=__shfl(sqa,srcQ), nqb=__shfl(sqb,srcQ);
        dgpa=(l9==8)?ndgqa:npa; dgqa=(l9==0)?ndgqa:nqa;
        dgpb=(l9==8)?ndgqb:npb; dgqb=(l9==0)?ndgqb:nqb;
      }
    }
    if(__all(smax < 3e-3f)) break;
  }
  { float n0=0.f,n1=0.f,m0=0.f,m1=0.f,o0=0.f,o1=0.f,p0=0.f,p1=0.f;
    #pragma unroll
    for(int k=0;k<18;k+=2){
      n0+=PA[k]*PA[k]; n1+=PA[k+1]*PA[k+1];
      m0+=QA[k]*QA[k]; m1+=QA[k+1]*QA[k+1];
      o0+=PB[k]*PB[k]; o1+=PB[k+1]*PB[k+1];
      p0+=QB[k]*QB[k]; p1+=QB[k+1]*QB[k+1];
    }
    dgpa=n0+n1; dgqa=m0+m1; dgpb=o0+o1; dgqb=p0+p1;
  }
}

// 14 matrices per 1-wave block (7 groups x 2 slots). Prep: Wa=W*a2 once;
// 1/tr and +1e-5I folded into spectral weights. Mc stride 21.
__global__ __launch_bounds__(64,1) void k_eighQKV(const float* __restrict__ Wq,
                                                  const float* __restrict__ Wk,
                                                  const float* __restrict__ Wv,
                                                  float* __restrict__ ws){
  __shared__ float S[7760];
  float* Wa  = S;          // 1080
  float* a2s = S+1080;     // 20
  float* Cs  = S+1100;     // 400
  float* Tt  = S+1500;     // 378
  float* Af  = S+1878;     // 324
  float* trs = S+2202;     // 14
  float* Mc  = S+2216;     // 14 x 378
  float* gl  = S+7508;     // 252
  int blk=blockIdx.x, tid=threadIdx.x;
  int g=tid/9, l9=tid-9*g;                       // g==7 -> lane 63 idle
  int srcP=min(g*9+((l9==8)?8:(l9+1)),63);
  int srcQ=g*9+((l9==0)?0:(l9-1));
  int ps=l9, qs=(l9==0)?17:(17-l9);

  if(tid<20) a2s[tid]=ws[OFF_A2+tid];
  __syncthreads();
  for(int i=tid;i<1080;i+=64){
    int m=i/360, r=i-m*360, row=r/18;
    const float* W=(m==0)?Wq:((m==1)?Wk:Wv);
    Wa[i]=W[r]*a2s[row];
  }
  __syncthreads();

  float PA[18],QA[18],PB[18],QB[18],dgpa,dgqa,dgpb,dgqb;
  #pragma unroll
  for(int k=0;k<18;k++){ PA[k]=0.f; QA[k]=0.f; PB[k]=0.f; QB[k]=0.f; }

  for(int gp_=0; gp_<14; gp_++){
    int id=min(blk*14+gp_,9215);
    int m=id/3072, bp=id-m*3072;
    const float* Cb=ws+OFF_C+(size_t)bp*400;
    for(int i=tid;i<400;i+=64) Cs[i]=Cb[i];
    __syncthreads();
    if(tid==63){
      float tr=0.f;
      #pragma unroll
      for(int i=0;i<20;i++) tr += Cs[i*20+i]*a2s[i]*a2s[i];
      trs[gp_]=tr;
    }
    const float* Wm=Wa+m*360;
    for(int idx=tid; idx<360; idx+=64){
      int a=idx/20, j=idx-a*20;
      float s=0.f;
      for(int i=0;i<20;i++) s += Wm[i*18+a]*Cs[i*20+j];
      Tt[a*21+j]=s;
    }
    __syncthreads();
    for(int idx=tid; idx<324; idx+=64){
      int a=idx/18, c=idx-a*18;
      float s=0.f;
      for(int j=0;j<20;j++) s += Tt[a*21+j]*Wm[j*18+c];
      Af[idx]=s;
    }
    __syncthreads();
    if(g==(gp_>>1)){
      float sh=1e-5f*trs[gp_];
      if((gp_&1)==0){
        #pragma unroll
        for(int k=0;k<18;k++){
          PA[k]=0.5f*(Af[k*18+ps]+Af[ps*18+k]) + ((k==ps)?sh:0.f);
          QA[k]=0.5f*(Af[k*18+qs]+Af[qs*18+k]) + ((k==qs)?sh:0.f);
        }
      } else {
        #pragma unroll
        for(int k=0;k<18;k++){
          PB[k]=0.5f*(Af[k*18+ps]+Af[ps*18+k]) + ((k==ps)?sh:0.f);
          QB[k]=0.5f*(Af[k*18+qs]+Af[qs*18+k]) + ((k==qs)?sh:0.f);
        }
      }
    }
    __syncthreads();
  }

  bl_jacobi2(PA,QA,PB,QB,dgpa,dgqa,dgpb,dgqb,l9,srcP,srcQ,8);

  if(g<7){
    float ltA=logf(trs[g*2]), ltB=logf(trs[g*2+1]);
    float dpa=fmaxf(dgpa,1e-30f), dqa=fmaxf(dgqa,1e-30f);
    float dpb=fmaxf(dgpb,1e-30f), dqb=fmaxf(dgqb,1e-30f);
    float gpa=__fdividef(0.5f*logf(dpa)-ltA, dpa);
    float gqa=__fdividef(0.5f*logf(dqa)-ltA, dqa);
    float gpb=__fdividef(0.5f*logf(dpb)-ltB, dpb);
    float gqb=__fdividef(0.5f*logf(dqb)-ltB, dqb);
    int mA=g*2, mB=g*2+1;
    #pragma unroll
    for(int k=0;k<18;k++){
      Mc[mA*378 + k*21 + ps]=PA[k];
      Mc[mA*378 + k*21 + qs]=QA[k];
      Mc[mB*378 + k*21 + ps]=PB[k];
      Mc[mB*378 + k*21 + qs]=QB[k];
    }
    gl[mA*18+ps]=gpa; gl[mA*18+qs]=gqa;
    gl[mB*18+ps]=gpb; gl[mB*18+qs]=gqb;
  }
  __syncthreads();
  // out[i][j] = sum_k gl[k]*Mc[i][k]*Mc[j][k]
  for(int idx=tid; idx<252; idx+=64){
    int mat=idx/18, i=idx-mat*18;
    int id=blk*14+mat;
    if(id<9216){
      int m=id/3072, bp=id-m*3072;
      float w[18];
      #pragma unroll
      for(int k=0;k<18;k++) w[k]=gl[mat*18+k]*Mc[mat*378+i*21+k];
      float* ob=ws+((m==0)?OFF_LQ:((m==1)?OFF_LK:OFF_LV))+(size_t)bp*324+i*18;
      for(int j=0;j<18;j++){
        float s=0.f;
        #pragma unroll
        for(int k=0;k<18;k++) s += w[k]*Mc[mat*378+j*21+k];
        ob[j]=s;
      }
    }
  }
}

// fused: energies + softmax + mean_log + eigh(+12I) + triu feat + linear.
// TWO batches per block (512 blocks); Jacobi groups 0-2 carry mat g of both.
__global__ __launch_bounds__(64,1) void k_att2(const float* __restrict__ lw,
                                               const float* __restrict__ lb,
                                               float* __restrict__ ws,
                                               float* __restrict__ out){
  __shared__ float lv[1944];    // 2x972; aliased as feat after ml
  __shared__ float lqk[3888];   // 2x(lq|lk); reused as ml
  __shared__ float e9[18];
  __shared__ float prob[18];
  __shared__ float Mc[2268];    // 6 x 378 (stride 21)
  __shared__ float gl[108];
  int blk=blockIdx.x, tid=threadIdx.x;
  for(int h=0;h<2;h++){
    int b=blk*2+h;
    const float4* LQ4=(const float4*)(ws+OFF_LQ+(size_t)b*972);
    const float4* LK4=(const float4*)(ws+OFF_LK+(size_t)b*972);
    const float4* LV4=(const float4*)(ws+OFF_LV+(size_t)b*972);
    float4* lqk4=(float4*)(lqk+h*1944); float4* lv4=(float4*)(lv+h*972);
    for(int i=tid;i<243;i+=64){ lqk4[i]=LQ4[i]; lqk4[243+i]=LK4[i]; lv4[i]=LV4[i]; }
  }
  __syncthreads();
  for(int h=0;h<2;h++){
    if(tid<36){
      int d=tid>>2, sub=tid&3;
      int ii=d/3, p=d-ii*3;
      const float* kk=lqk+h*1944+972+ii*324+sub*81;
      const float* qq=lqk+h*1944+p*324+sub*81;
      float s=0.f;
      for(int el=0;el<81;el++){ float dd=kk[el]-qq[el]; s+=dd*dd; }
      s += __shfl_xor(s,1); s += __shfl_xor(s,2);
      if(sub==0) e9[h*9+d]=s;
    }
  }
  __syncthreads();
  if(tid<6){
    int h=tid/3, p=tid-h*3;
    float f0=1.f/(1.f+log1pf(e9[h*9+0+p]));
    float f1=1.f/(1.f+log1pf(e9[h*9+3+p]));
    float f2=1.f/(1.f+log1pf(e9[h*9+6+p]));
    float mx=fmaxf(f0,fmaxf(f1,f2));
    float x0=expf(f0-mx), x1=expf(f1-mx), x2=expf(f2-mx);
    float inv=1.f/(x0+x1+x2);
    prob[h*9+p*3+0]=x0*inv; prob[h*9+p*3+1]=x1*inv; prob[h*9+p*3+2]=x2*inv;
  }
  __syncthreads();
  for(int idx=tid; idx<1944; idx+=64){
    int h=idx/972, r=idx-h*972;
    int p=r/324, el=r-p*324;
    const float* lvh=lv+h*972;
    lqk[h*1944+r]=prob[h*9+p*3+0]*lvh[el]+prob[h*9+p*3+1]*lvh[324+el]+prob[h*9+p*3+2]*lvh[648+el];
    // note: writes land in the lq half (r<972); lk half becomes dead
  }
  __syncthreads();
  int g=tid/9, l9=tid-9*g;
  int srcP=min(g*9+((l9==8)?8:(l9+1)),63);
  int srcQ=g*9+((l9==0)?0:(l9-1));
  int ps=l9, qs=(l9==0)?17:(17-l9);
  float PA[18],QA[18],PB[18],QB[18],dgpa,dgqa,dgpb,dgqb;
  if(g<3){
    const float* Ag0=lqk+g*324;
    const float* Ag1=lqk+1944+g*324;
    #pragma unroll
    for(int k=0;k<18;k++){
      PA[k]=0.5f*(Ag0[k*18+ps]+Ag0[ps*18+k]) + ((k==ps)?12.f:0.f);
      QA[k]=0.5f*(Ag0[k*18+qs]+Ag0[qs*18+k]) + ((k==qs)?12.f:0.f);
      PB[k]=0.5f*(Ag1[k*18+ps]+Ag1[ps*18+k]) + ((k==ps)?12.f:0.f);
      QB[k]=0.5f*(Ag1[k*18+qs]+Ag1[qs*18+k]) + ((k==qs)?12.f:0.f);
    }
  } else {
    #pragma unroll
    for(int k=0;k<18;k++){ PA[k]=0.f; QA[k]=0.f; PB[k]=0.f; QB[k]=0.f; }
  }
  __syncthreads();
  bl_jacobi2(PA,QA,PB,QB,dgpa,dgqa,dgpb,dgqb,l9,srcP,srcQ,8);
  if(g<3){
    float lpa=sqrtf(dgpa), lqa=sqrtf(dgqa), lpb=sqrtf(dgpb), lqb=sqrtf(dgqb);
    float gpa=__fdividef(fmaxf(lpa-12.f,-9.2103404f), fmaxf(dgpa,1e-12f));
    float gqa=__fdividef(fmaxf(lqa-12.f,-9.2103404f), fmaxf(dgqa,1e-12f));
    float gpb=__fdividef(fmaxf(lpb-12.f,-9.2103404f), fmaxf(dgpb,1e-12f));
    float gqb=__fdividef(fmaxf(lqb-12.f,-9.2103404f), fmaxf(dgqb,1e-12f));
    int mA=g, mB=3+g;
    #pragma unroll
    for(int k=0;k<18;k++){
      Mc[mA*378 + k*21 + ps]=PA[k];
      Mc[mA*378 + k*21 + qs]=QA[k];
      Mc[mB*378 + k*21 + ps]=PB[k];
      Mc[mB*378 + k*21 + qs]=QB[k];
    }
    gl[mA*18+ps]=gpa; gl[mA*18+qs]=gqa;
    gl[mB*18+ps]=gpb; gl[mB*18+qs]=gqb;
  }
  __syncthreads();
  // triu(tang) -> feat in LDS (feat_h at lv + h*972, lv dead)
  for(int idx=tid; idx<108; idx+=64){
    int h=idx/54, rt=idx-h*54;
    int mat=rt/18, i=rt-mat*18;
    int mi = h*3+mat;
    float w[18];
    #pragma unroll
    for(int k=0;k<18;k++) w[k]=gl[mi*18+k]*Mc[mi*378+i*21+k];
    float* feat = lv + h*972;
    int base = mat*171 + (i*18 - (i*(i-1))/2) - i;
    for(int j=i;j<18;j++){
      float s=0.f;
      #pragma unroll
      for(int k=0;k<18;k++) s += w[k]*Mc[mi*378+j*21+k];
      feat[base+j]=s;
    }
  }
  __syncthreads();
  int j4 = tid&3, chunk = tid>>2;
  const float* wj = lw + j4*513;
  for(int h=0;h<2;h++){
    const float* feat = lv + h*972;
    float s=0.f;
    for(int k=chunk; k<513; k+=16) s += feat[k]*wj[k];
    s += __shfl_xor(s,4); s += __shfl_xor(s,8);
    s += __shfl_xor(s,16); s += __shfl_xor(s,32);
    if(chunk==0) out[(blk*2+h)*4+j4] = s + lb[j4];
  }
}

extern "C" void kernel_launch(void* const* d_in, const int* in_sizes, int n_in,
                              void* d_out, int out_size, void* d_ws, size_t ws_size,
                              hipStream_t stream){
  const float* x  =(const float*)d_in[0];
  const float* w1 =(const float*)d_in[1];
  const float* cb1=(const float*)d_in[2];
  const float* g1 =(const float*)d_in[3];
  const float* bb1=(const float*)d_in[4];
  const float* w2 =(const float*)d_in[5];
  // d_in[6] conv2_b, d_in[8] bn2_b: provably cancel
  const float* g2 =(const float*)d_in[7];
  const float* Wq =(const float*)d_in[9];
  const float* Wk =(const float*)d_in[10];
  const float* Wv =(const float*)d_in[11];
  const float* lw =(const float*)d_in[12];
  const float* lb =(const float*)d_in[13];
  float* ws=(float*)d_ws;
  float* out=(float*)d_out;

  k_zero<<<1,256,0,stream>>>(ws);
  k_moment<<<B_,256,0,stream>>>(x,ws);
  k_prep<<<1,256,0,stream>>>(w1,cb1,g1,bb1,w2,ws);
  k_cov<<<B_,256,0,stream>>>(x,ws);
  k_fin2<<<1,64,0,stream>>>(g2,ws);
  k_eighQKV<<<659,64,0,stream>>>(Wq,Wk,Wv,ws);   // 14 matrices per wave
  k_att2<<<512,64,0,stream>>>(lw,lb,ws,out);     // 2 batches per block
}

// Round 11
// 406.263 us; speedup vs baseline: 1.6558x; 1.6558x over previous
//
#include <hip/hip_runtime.h>
#include <cmath>

#define B_ 1024
#define CIN_ 22
#define T1_ 438
#define COUT_ 20
#define T2_ 439

// ws float offsets
#define OFF_S 0
#define OFF_M 32
#define OFF_SUM2 576
#define OFF_SSQ2 608
#define OFF_A2 640
#define OFF_ACC_END 704
#define OFF_C 1024
#define OFF_LQ (OFF_C + B_*3*400)
#define OFF_LK (OFF_LQ + B_*3*324)
#define OFF_LV (OFF_LK + B_*3*324)
#define OFF_WEFF (OFF_LV + B_*3*324)
#define OFF_BPRE (OFF_WEFF + 5280)

__global__ __launch_bounds__(256) void k_zero(float* ws){
  for(int i=threadIdx.x; i<OFF_ACC_END; i+=256) ws[i]=0.f;
}

// bn1 stats via second-moment matrix of x: S[22], M[22][22] (triu), float4 dots
__global__ __launch_bounds__(256) void k_moment(const float* __restrict__ x, float* __restrict__ ws){
  __shared__ float xs[CIN_][440];
  int b=blockIdx.x;
  const float* xb = x + (size_t)b*CIN_*T1_;
  for(int i=threadIdx.x;i<CIN_*T1_;i+=256){
    int h=i/T1_, t=i-h*T1_;
    xs[h][t]=xb[i];
  }
  if(threadIdx.x<CIN_){ xs[threadIdx.x][438]=0.f; xs[threadIdx.x][439]=0.f; }
  __syncthreads();
  for(int tgt=threadIdx.x; tgt<275; tgt+=256){
    if(tgt<253){
      int r=tgt, i=0;
      while(true){ int c=CIN_-i; if(r<c) break; r-=c; i++; }
      int j=i+r;
      const float4* ri=(const float4*)&xs[i][0];
      const float4* rj=(const float4*)&xs[j][0];
      float acc=0.f;
      for(int t=0;t<110;t++){
        float4 a=ri[t], bb=rj[t];
        acc += a.x*bb.x + a.y*bb.y + a.z*bb.z + a.w*bb.w;
      }
      atomicAdd(&ws[OFF_M + i*CIN_ + j], acc);
    } else {
      int c=tgt-253;
      const float4* rc=(const float4*)&xs[c][0];
      float acc=0.f;
      for(int t=0;t<110;t++){
        float4 a=rc[t];
        acc += a.x + a.y + a.z + a.w;
      }
      atomicAdd(&ws[OFF_S + c], acc);
    }
  }
}

// bn1 closed-form + fold conv1/bn1 into conv2: Weff[o][h][k], bias prefix pre[o][13]
__global__ __launch_bounds__(256) void k_prep(const float* __restrict__ w1, const float* __restrict__ cb1,
                                              const float* __restrict__ g1, const float* __restrict__ bb1,
                                              const float* __restrict__ w2, float* __restrict__ ws){
  __shared__ float a1s[CIN_], e1s[CIN_];
  int tid=threadIdx.x;
  if(tid<CIN_){
    int c=tid;
    const double N = (double)B_*T1_;
    double wS=0.0, wMw=0.0;
    for(int h=0;h<CIN_;h++) wS += (double)w1[c*CIN_+h]*(double)ws[OFF_S+h];
    for(int h=0;h<CIN_;h++){
      for(int h2=0;h2<CIN_;h2++){
        int i=h<h2?h:h2, j=h<h2?h2:h;
        wMw += (double)w1[c*CIN_+h]*(double)w1[c*CIN_+h2]*(double)ws[OFF_M+i*CIN_+j];
      }
    }
    double bc=cb1[c];
    double mean=wS/N+bc;
    double ex2=(wMw+2.0*bc*wS)/N+bc*bc;
    double var=ex2-mean*mean;
    double a1=(double)g1[c]/sqrt(var+1e-5);
    double d1=(double)bb1[c]-mean*a1;
    a1s[c]=(float)a1;
    e1s[c]=(float)(a1*bc+d1);
  }
  __syncthreads();
  for(int idx=tid; idx<5280; idx+=256){
    int o=idx/264, r=idx-o*264, h=r/12, k=r-h*12;
    float s=0.f;
    for(int i=0;i<CIN_;i++) s += w2[(o*CIN_+i)*12+k]*a1s[i]*w1[i*CIN_+h];
    ws[OFF_WEFF+idx]=s;
  }
  if(tid<COUT_){
    float pre=0.f;
    ws[OFF_BPRE+tid*13+0]=0.f;
    for(int k=0;k<12;k++){
      float wb=0.f;
      for(int i=0;i<CIN_;i++) wb += w2[(tid*CIN_+i)*12+k]*e1s[i];
      pre += wb;
      ws[OFF_BPRE+tid*13+k+1]=pre;
    }
  }
}

// direct conv x->h2 (folded kernel) + per-patch covariance + bn2 sums.
__global__ __launch_bounds__(256) void k_cov(const float* __restrict__ x,
                                             float* __restrict__ ws){
  __shared__ float Wl[5280];
  __shared__ float preL[COUT_][13];
  __shared__ float xs[CIN_][168];
  __shared__ float h2w[COUT_][156];
  __shared__ float pmu[COUT_];
  int b=blockIdx.x, tid=threadIdx.x;
  for(int i=tid;i<5280;i+=256) Wl[i]=ws[OFF_WEFF+i];
  for(int i=tid;i<260;i+=256) ((float*)preL)[i]=ws[OFF_BPRE+i];
  int pi=0,pj=0;
  if(tid<210){ int r=tid,i=0; while(true){int c=COUT_-i; if(r<c)break; r-=c; i++;} pi=i; pj=i+r; }
  int sc = tid-210;
  float ac1=0.f, ac2=0.f;
  const float* xb = x + (size_t)b*CIN_*T1_;
  int o = tid/12, cch = tid-12*o;
  int t0 = cch*13;
  for(int p=0;p<3;p++){
    const int off = (p==0)?0:((p==1)?147:293);
    const int L = (p==0)?147:146;
    __syncthreads();
    for(int idx=tid; idx<CIN_*168; idx+=256){
      int h=idx/168, c2=idx-h*168;
      int gxt = off-6+c2;
      xs[h][c2] = (c2<167 && gxt>=0 && gxt<T1_) ? xb[h*T1_+gxt] : 0.f;
    }
    __syncthreads();
    if(tid<240){
      float acc[13];
      #pragma unroll
      for(int j=0;j<13;j++){
        int gt = off+t0+j;
        int kmin = 6-gt; kmin = kmin<0?0:kmin;
        int kmax = 443-gt; kmax = kmax>11?11:kmax;
        acc[j] = (kmax>=kmin)? preL[o][kmax+1]-preL[o][kmin] : 0.f;
      }
      const float* Wo = &Wl[o*264];
      for(int h=0;h<CIN_;h++){
        float xw[24];
        #pragma unroll
        for(int c2=0;c2<24;c2++) xw[c2]=xs[h][t0+c2];
        const float* Wh = Wo + h*12;
        #pragma unroll
        for(int k=0;k<12;k++){
          float w=Wh[k];
          #pragma unroll
          for(int j=0;j<13;j++) acc[j] += w*xw[j+k];
        }
      }
      #pragma unroll
      for(int j=0;j<13;j++) if(t0+j<L) h2w[o][t0+j]=acc[j];
    } else {
      int npad = 156-L;
      for(int z=tid-240; z<COUT_*npad; z+=16){
        int oo=z/npad, c2=z-oo*npad;
        h2w[oo][L+c2]=0.f;
      }
    }
    __syncthreads();
    float s=0.f;
    if(tid<210){
      const float4* ri=(const float4*)&h2w[pi][0];
      const float4* rj=(const float4*)&h2w[pj][0];
      for(int t=0;t<39;t++){
        float4 a=ri[t], bb=rj[t];
        s += a.x*bb.x + a.y*bb.y + a.z*bb.z + a.w*bb.w;
      }
    } else if(sc>=0 && sc<COUT_){
      const float4* rc=(const float4*)&h2w[sc][0];
      float s1=0.f,s2=0.f;
      for(int t=0;t<39;t++){
        float4 a=rc[t];
        s1 += a.x+a.y+a.z+a.w;
        s2 += a.x*a.x+a.y*a.y+a.z*a.z+a.w*a.w;
      }
      ac1+=s1; ac2+=s2; pmu[sc]=s1/(float)L;
    }
    __syncthreads();
    if(tid<210){
      s -= (float)L*pmu[pi]*pmu[pj];
      float* Cb = ws + OFF_C + ((size_t)b*3+p)*400;
      Cb[pi*COUT_+pj]=s; Cb[pj*COUT_+pi]=s;
    }
  }
  if(sc>=0 && sc<COUT_){
    atomicAdd(&ws[OFF_SUM2+sc], ac1);
    atomicAdd(&ws[OFF_SSQ2+sc], ac2);
  }
}

__global__ void k_fin2(const float* __restrict__ g2, float* __restrict__ ws){
  int c=threadIdx.x; if(c>=COUT_) return;
  const double N=(double)B_*T2_;
  double m=ws[OFF_SUM2+c]/N;
  double v=ws[OFF_SSQ2+c]/N - m*m;
  ws[OFF_A2+c]=(float)((double)g2[c]/sqrt(v+1e-5));
}

// ---------------------------------------------------------------------------
// One-sided Jacobi, ONE COLUMN PER LANE (18 lanes/matrix, 3 matrices/wave).
// Columns never migrate; the tournament PAIRING rotates instead (circle
// method): round r pairs label a<17 with (2r-a) mod 17, and label 17 with
// (r mod 17); self-pair (a==r mod 17) maps to partner 17. Identical rotation
// set to Brent-Luk. Per round: ONE batch of 19 bpermutes (partner col + dg),
// local dot, rotate own column only. ~60 live VGPRs -> the batch pipelines
// (R9/R10 lesson: 2-col migration needed >110 VGPRs, got ~90, serialized).
// V-free: converged cols = lambda*u; dg = lambda^2.
// ---------------------------------------------------------------------------
__device__ __forceinline__ void bl_jacobi18(float own[18], float &dgo,
                                            int l18, int gb, bool act, int maxsweep){
  int self = gb + l18;
  for(int sweep=0; sweep<maxsweep; sweep++){
    { float d0=0.f,d1=0.f;
      #pragma unroll
      for(int k=0;k<18;k+=2){ d0+=own[k]*own[k]; d1+=own[k+1]*own[k+1]; }
      dgo=d0+d1;
    }
    float smax=0.f;
    for(int r=0;r<17;r++){
      int t = 2*r - l18;
      t += (t<0)?17:0;
      t -= (t>=17)?17:0;
      int pa = (l18==17)? r : ((t==l18)?17:t);
      int src = act ? (gb + pa) : self;
      float oth[18];
      #pragma unroll
      for(int k=0;k<18;k++) oth[k]=__shfl(own[k], src);
      float dgx = __shfl(dgo, src);
      float a0=0.f,a1=0.f;
      #pragma unroll
      for(int k=0;k<18;k+=2){ a0+=own[k]*oth[k]; a1+=own[k+1]*oth[k+1]; }
      float apq=a0+a1;
      bool isP = l18 < pa;
      float dgp = isP? dgo : dgx;
      float dgq = isP? dgx : dgo;
      float tau = __fdividef(dgq-dgp, 2.f*apq);
      float tt  = __fdividef(copysignf(1.f,tau), fabsf(tau)+sqrtf(1.f+tau*tau));
      float c   = rsqrtf(1.f+tt*tt);
      float s   = tt*c;
      bool  z   = (apq==0.f) || !act;
      tt=z?0.f:tt; c=z?1.f:c; s=z?0.f:s;
      smax=fmaxf(smax,fabsf(s));
      float sgn = isP ? -s : s;       // p: c*p - s*q ; q: s*p + c*q
      #pragma unroll
      for(int k=0;k<18;k++) own[k] = c*own[k] + sgn*oth[k];
      dgo = isP ? (dgp - tt*apq) : (dgq + tt*apq);
    }
    if(__all(smax<3e-3f)) break;
  }
  float d0=0.f,d1=0.f;
  #pragma unroll
  for(int k=0;k<18;k+=2){ d0+=own[k]*own[k]; d1+=own[k+1]*own[k+1]; }
  dgo=d0+d1;
}

// One (b,p) per 1-wave block: stage C once, 3 congruences (Wa=W*a2; 1/tr and
// +1e-5I folded into spectral weights), 3x18-lane Jacobi, logm -> LQ/LK/LV.
// 3072 blocks = 3 waves/SIMD.
__global__ __launch_bounds__(64) void k_eigh3(const float* __restrict__ Wq,
                                              const float* __restrict__ Wk,
                                              const float* __restrict__ Wv,
                                              float* __restrict__ ws){
  __shared__ float S[2933];
  float* Wa  = S;          // 1080 (3x360, a2-folded); aliased as Mc after Jacobi
  float* a2s = S+1080;     // 20
  float* Cs  = S+1100;     // 400
  float* Tt  = S+1500;     // 378 (18x21)
  float* ob  = S+1878;     // 972 (3x324): congruence out, then logm staging
  float* gl  = S+2850;     // 54
  float* trp = S+2904;     // 1
  int bp=blockIdx.x, tid=threadIdx.x;
  int g=tid/18, l18=tid-18*g;       // g==3 (lanes 54-63) idle for Jacobi
  bool act = (g<3);
  int gb = g*18;

  if(tid<20) a2s[tid]=ws[OFF_A2+tid];
  __syncthreads();
  for(int i=tid;i<1080;i+=64){
    int m=i/360, r=i-m*360, row=r/18;
    const float* W=(m==0)?Wq:((m==1)?Wk:Wv);
    Wa[i]=W[r]*a2s[row];
  }
  const float* Cb=ws+OFF_C+(size_t)bp*400;
  for(int i=tid;i<400;i+=64) Cs[i]=Cb[i];
  __syncthreads();
  if(tid==0){
    float tr=0.f;
    #pragma unroll
    for(int i=0;i<20;i++) tr += Cs[i*20+i]*a2s[i]*a2s[i];
    trp[0]=tr;
  }
  __syncthreads();
  float tr=trp[0];
  float sh=1e-5f*tr;
  float logtr=logf(tr);
  // 3 congruences: B_m = Wa_m^T C Wa_m
  for(int m=0;m<3;m++){
    const float* Wm=Wa+m*360;
    for(int idx=tid; idx<360; idx+=64){
      int a=idx/20, j=idx-a*20;
      float s=0.f;
      for(int i=0;i<20;i++) s += Wm[i*18+a]*Cs[i*20+j];
      Tt[a*21+j]=s;
    }
    __syncthreads();
    for(int idx=tid; idx<324; idx+=64){
      int a=idx/18, c=idx-a*18;
      float s=0.f;
      for(int j=0;j<20;j++) s += Tt[a*21+j]*Wm[j*18+c];
      ob[m*324+idx]=s;
    }
    __syncthreads();
  }
  float own[18], dgo=0.f;
  if(act){
    const float* Ag=ob+g*324;
    #pragma unroll
    for(int k=0;k<18;k++)
      own[k]=0.5f*(Ag[k*18+l18]+Ag[l18*18+k]) + ((k==l18)?sh:0.f);
  } else {
    #pragma unroll
    for(int k=0;k<18;k++) own[k]=0.f;
  }
  __syncthreads();
  bl_jacobi18(own,dgo,l18,gb,act,8);
  // lambda_true = sqrt(dg)/tr; weight = (0.5*log(dg)-log(tr))/dg
  float dp=fmaxf(dgo,1e-30f);
  float gv=__fdividef(0.5f*logf(dp)-logtr, dp);
  float* Mc = Wa;  // Wa dead; Mc layout [mat][elem*19 + col], 3x342
  if(act){
    #pragma unroll
    for(int k=0;k<18;k++) Mc[g*342 + k*19 + l18]=own[k];
    gl[g*18+l18]=gv;
  }
  __syncthreads();
  // out[i][j] = sum_k gl[k]*Mc[i][k]*Mc[j][k]
  if(tid<54){
    int mat=tid/18, i=tid-mat*18;
    float w[18];
    #pragma unroll
    for(int k=0;k<18;k++) w[k]=gl[mat*18+k]*Mc[mat*342+i*19+k];
    for(int j=0;j<18;j++){
      float s=0.f;
      #pragma unroll
      for(int k=0;k<18;k++) s += w[k]*Mc[mat*342+j*19+k];
      ob[mat*324+i*18+j]=s;
    }
  }
  __syncthreads();
  const float4* s4=(const float4*)ob;
  for(int i=tid;i<243;i+=64){
    int mat=i/81, r=i-mat*81;
    float4* dst=(float4*)(ws + ((mat==0)?OFF_LQ:((mat==1)?OFF_LK:OFF_LV)) + (size_t)bp*324);
    dst[r]=s4[i];
  }
}

// fused: energies + softmax + mean_log + eigh(+12I) + triu feat + linear out
__global__ __launch_bounds__(64) void k_att2(const float* __restrict__ lw,
                                             const float* __restrict__ lb,
                                             float* __restrict__ ws,
                                             float* __restrict__ out){
  __shared__ float lv[972];     // aliased as feat after ml
  __shared__ float lqk[1944];   // lq | lk ; reused as ml
  __shared__ float e9[9];
  __shared__ float prob[9];
  __shared__ float Mc[1026];    // 3 x 342
  __shared__ float gl[54];
  int b=blockIdx.x, tid=threadIdx.x;
  const float4* LQ4=(const float4*)(ws+OFF_LQ+(size_t)b*972);
  const float4* LK4=(const float4*)(ws+OFF_LK+(size_t)b*972);
  const float4* LV4=(const float4*)(ws+OFF_LV+(size_t)b*972);
  float4* lqk4=(float4*)lqk; float4* lv4=(float4*)lv;
  for(int i=tid;i<243;i+=64){ lqk4[i]=LQ4[i]; lqk4[243+i]=LK4[i]; lv4[i]=LV4[i]; }
  __syncthreads();
  if(tid<36){
    int d=tid>>2, sub=tid&3;
    int ii=d/3, p=d-ii*3;
    const float* kk=lqk+972+ii*324+sub*81;
    const float* qq=lqk+p*324+sub*81;
    float s=0.f;
    for(int el=0;el<81;el++){ float dd=kk[el]-qq[el]; s+=dd*dd; }
    s += __shfl_xor(s,1); s += __shfl_xor(s,2);
    if(sub==0) e9[d]=s;
  }
  __syncthreads();
  if(tid<3){
    int p=tid;
    float f0=1.f/(1.f+log1pf(e9[0+p]));
    float f1=1.f/(1.f+log1pf(e9[3+p]));
    float f2=1.f/(1.f+log1pf(e9[6+p]));
    float mx=fmaxf(f0,fmaxf(f1,f2));
    float x0=expf(f0-mx), x1=expf(f1-mx), x2=expf(f2-mx);
    float inv=1.f/(x0+x1+x2);
    prob[p*3+0]=x0*inv; prob[p*3+1]=x1*inv; prob[p*3+2]=x2*inv;
  }
  __syncthreads();
  float* ml = lqk;
  for(int idx=tid; idx<972; idx+=64){
    int p=idx/324, el=idx-p*324;
    ml[idx]=prob[p*3+0]*lv[el]+prob[p*3+1]*lv[324+el]+prob[p*3+2]*lv[648+el];
  }
  __syncthreads();
  int g=tid/18, l18=tid-18*g;
  bool act=(g<3);
  int gb=g*18;
  float own[18], dgo=0.f;
  if(act){
    const float* Ag=ml+g*324;
    #pragma unroll
    for(int k=0;k<18;k++)
      own[k]=0.5f*(Ag[k*18+l18]+Ag[l18*18+k]) + ((k==l18)?12.f:0.f);
  } else {
    #pragma unroll
    for(int k=0;k<18;k++) own[k]=0.f;
  }
  __syncthreads();
  bl_jacobi18(own,dgo,l18,gb,act,8);
  float lam=sqrtf(fmaxf(dgo,1e-12f));
  float gv=__fdividef(fmaxf(lam-12.f,-9.2103404f), fmaxf(dgo,1e-12f));
  if(act){
    #pragma unroll
    for(int k=0;k<18;k++) Mc[g*342 + k*19 + l18]=own[k];
    gl[g*18+l18]=gv;
  }
  __syncthreads();
  float* feat = lv;   // lv dead
  if(tid<54){
    int mat=tid/18, i=tid-mat*18;
    float w[18];
    #pragma unroll
    for(int k=0;k<18;k++) w[k]=gl[mat*18+k]*Mc[mat*342+i*19+k];
    int base = mat*171 + (i*18 - (i*(i-1))/2) - i;
    for(int j=i;j<18;j++){
      float s=0.f;
      #pragma unroll
      for(int k=0;k<18;k++) s += w[k]*Mc[mat*342+j*19+k];
      feat[base+j]=s;
    }
  }
  __syncthreads();
  int j4 = tid&3, chunk = tid>>2;
  float s=0.f;
  const float* wj = lw + j4*513;
  for(int k=chunk; k<513; k+=16) s += feat[k]*wj[k];
  s += __shfl_xor(s,4); s += __shfl_xor(s,8);
  s += __shfl_xor(s,16); s += __shfl_xor(s,32);
  if(chunk==0) out[b*4+j4] = s + lb[j4];
}

extern "C" void kernel_launch(void* const* d_in, const int* in_sizes, int n_in,
                              void* d_out, int out_size, void* d_ws, size_t ws_size,
                              hipStream_t stream){
  const float* x  =(const float*)d_in[0];
  const float* w1 =(const float*)d_in[1];
  const float* cb1=(const float*)d_in[2];
  const float* g1 =(const float*)d_in[3];
  const float* bb1=(const float*)d_in[4];
  const float* w2 =(const float*)d_in[5];
  // d_in[6] conv2_b, d_in[8] bn2_b: provably cancel
  const float* g2 =(const float*)d_in[7];
  const float* Wq =(const float*)d_in[9];
  const float* Wk =(const float*)d_in[10];
  const float* Wv =(const float*)d_in[11];
  const float* lw =(const float*)d_in[12];
  const float* lb =(const float*)d_in[13];
  float* ws=(float*)d_ws;
  float* out=(float*)d_out;

  k_zero<<<1,256,0,stream>>>(ws);
  k_moment<<<B_,256,0,stream>>>(x,ws);
  k_prep<<<1,256,0,stream>>>(w1,cb1,g1,bb1,w2,ws);
  k_cov<<<B_,256,0,stream>>>(x,ws);
  k_fin2<<<1,64,0,stream>>>(g2,ws);
  k_eigh3<<<3072,64,0,stream>>>(Wq,Wk,Wv,ws);   // one (b,p) per wave, 18 lanes/matrix
  k_att2<<<B_,64,0,stream>>>(lw,lb,ws,out);     // fused att+eigh2+feat+linear
}